// Round 16
// baseline (447.166 us; speedup 1.0000x reference)
//
#include <hip/hip_runtime.h>
#include <hip/hip_bf16.h>

#define FEAT 256
#define HDIM 256
#define CDIM 64
#define THETA 0.5f
#define APAD 264  // A-tile LDS row stride in bf16 elems

typedef float floatx2 __attribute__((ext_vector_type(2)));
typedef __attribute__((ext_vector_type(8))) short bf16x8;
typedef __attribute__((ext_vector_type(4))) float f32x4;

// ---------------- conversions ----------------
__device__ __forceinline__ unsigned short f2bf(float f) {
    unsigned int u = __float_as_uint(f);
    u += 0x7fffu + ((u >> 16) & 1u);
    return (unsigned short)(u >> 16);
}
__device__ __forceinline__ unsigned char f2f8(float f) {
    int w = __builtin_amdgcn_cvt_pk_fp8_f32(f, f, 0, false);
    return (unsigned char)(w & 0xff);
}

// ---------------- MEGA-PREP: 3-way degree count | transposeW x2 | transposeWy ----------------
// deg3 = [deg | posDeg | negDeg], each length N
__global__ __launch_bounds__(256) void prep(const int* __restrict__ e0, const int* __restrict__ e1,
                                            const int* __restrict__ n0, const int* __restrict__ n1,
                                            int* deg3,
                                            const float* __restrict__ W1, unsigned short* __restrict__ Wt1,
                                            const float* __restrict__ W2, unsigned short* __restrict__ Wt2,
                                            const float* __restrict__ Wy, unsigned short* __restrict__ WyT,
                                            int E, int N, int ebk) {
    const int b = blockIdx.x;
    const int tid = threadIdx.x;
    if (b < ebk) {
        const int i = b * 256 + tid;
        if (i < E) {
            int a = e0[i], bb = e1[i];
            atomicAdd(&deg3[a], 1);
            if (a < bb) atomicAdd(&deg3[N + a], 1);
            int c = n0[i], d = n1[i];
            if (c < d) atomicAdd(&deg3[2 * N + c], 1);
        }
    } else if (b < ebk + 256) {
        int k = b - ebk;
        Wt1[(size_t)tid * 256 + k] = f2bf(W1[(size_t)k * 256 + tid]);
    } else if (b < ebk + 512) {
        int k = b - ebk - 256;
        Wt2[(size_t)tid * 256 + k] = f2bf(W2[(size_t)k * 256 + tid]);
    } else {
        int b3 = b - ebk - 512;  // 0..63
        int n = tid & 63;
        int k = b3 * 4 + (tid >> 6);
        WyT[(size_t)n * 256 + k] = f2bf(Wy[(size_t)k * 64 + n]);
    }
}

// ---------------- scan1 + dinv: in-block prefix of 3 degree arrays ----------------
// writes partial (in-block exclusive) prefixes to rowptr/posCur/negCur; block totals to blkS3[3][nbn]
__global__ __launch_bounds__(256) void scan1_dinv(const int* __restrict__ deg3,
                                                  int* __restrict__ rowptr,
                                                  int* __restrict__ posCur,
                                                  int* __restrict__ negCur,
                                                  int* __restrict__ blkS3,
                                                  float* __restrict__ dinv, int N, int nbn) {
    __shared__ int s0[256], s1[256], s2[256];
    const int tid = threadIdx.x;
    const int i = blockIdx.x * 256 + tid;
    int v0 = (i < N) ? deg3[i] : 0;
    int v1 = (i < N) ? deg3[N + i] : 0;
    int v2 = (i < N) ? deg3[2 * N + i] : 0;
    if (i < N) dinv[i] = rsqrtf((float)(v0 + 1));
    s0[tid] = v0; s1[tid] = v1; s2[tid] = v2;
    __syncthreads();
#pragma unroll
    for (int off = 1; off < 256; off <<= 1) {
        int t0 = (tid >= off) ? s0[tid - off] : 0;
        int t1 = (tid >= off) ? s1[tid - off] : 0;
        int t2 = (tid >= off) ? s2[tid - off] : 0;
        __syncthreads();
        s0[tid] += t0; s1[tid] += t1; s2[tid] += t2;
        __syncthreads();
    }
    if (i < N) {
        rowptr[i] = s0[tid] - v0;
        posCur[i] = s1[tid] - v1;
        negCur[i] = s2[tid] - v2;
    }
    if (tid == 255) {
        blkS3[blockIdx.x] = s0[255];
        blkS3[nbn + blockIdx.x] = s1[255];
        blkS3[2 * nbn + blockIdx.x] = s2[255];
    }
}

// ---------------- scan2: single block scans the 3 block-sum arrays; totals -> cnt ----------------
__global__ __launch_bounds__(256) void scan2(int* __restrict__ blkS3, int* __restrict__ cnt, int nbn) {
    __shared__ int part[256];
    const int tid = threadIdx.x;
    const int chunk = (nbn + 255) / 256;
    for (int z = 0; z < 3; ++z) {
        int* arr = blkS3 + z * nbn;
        const int s = tid * chunk;
        const int e = min(s + chunk, nbn);
        int sum = 0;
        for (int i = s; i < e; ++i) sum += arr[i];
        part[tid] = sum;
        __syncthreads();
#pragma unroll
        for (int off = 1; off < 256; off <<= 1) {
            int t = (tid >= off) ? part[tid - off] : 0;
            __syncthreads();
            part[tid] += t;
            __syncthreads();
        }
        int run = part[tid] - sum;
        for (int i = s; i < e; ++i) {
            int v = arr[i];
            arr[i] = run;
            run += v;
        }
        if (tid == 255 && z == 1) cnt[0] = run;
        if (tid == 255 && z == 2) cnt[1] = run;
        __syncthreads();
    }
}

// ---------------- scan3: add block offsets; emit cursor copies ----------------
__global__ __launch_bounds__(256) void scan3(int* __restrict__ rowptr, int* __restrict__ cursor,
                                             int* __restrict__ posCur, int* __restrict__ negCur,
                                             const int* __restrict__ blkS3, int N, int E, int nbn) {
    const int b = blockIdx.x;
    const int i = b * 256 + threadIdx.x;
    if (i < N) {
        int v = rowptr[i] + blkS3[b];
        rowptr[i] = v;
        cursor[i] = v;
        posCur[i] += blkS3[nbn + b];
        negCur[i] += blkS3[2 * nbn + b];
    }
    if (i == 0) rowptr[N] = E;
}

// ---------------- bucket: CSR colIdx + pos/neg lists bucketed by first node ----------------
__global__ __launch_bounds__(256) void bucket_all(const int* __restrict__ e0, const int* __restrict__ e1,
                                                  const int* __restrict__ n0, const int* __restrict__ n1,
                                                  const float* __restrict__ ls,
                                                  int* cursor, int* posCur, int* negCur,
                                                  int* __restrict__ colIdx,
                                                  int2* __restrict__ posAB, float* __restrict__ posLS,
                                                  int2* __restrict__ negCD, int E) {
    int i = blockIdx.x * 256 + threadIdx.x;
    if (i >= E) return;
    int a = e0[i], b = e1[i];
    int p = atomicAdd(&cursor[a], 1);
    colIdx[p] = b;
    if (a < b) {
        int j = atomicAdd(&posCur[a], 1);
        posAB[j] = make_int2(a, b);
        posLS[j] = ls[i];
    }
    int c = n0[i], d = n1[i];
    if (c < d) {
        int k = atomicAdd(&negCur[c], 1);
        negCD[k] = make_int2(c, d);
    }
}

// ---------------- MFMA core: emits g = fp8(dinv[row] * acc) ----------------
__device__ __forceinline__ void gemm_core_f8out(const unsigned short* Al,
                                                const float* sd,
                                                const unsigned short* __restrict__ Wt,
                                                unsigned char* __restrict__ out,
                                                int m0, int wv, int lane, int M) {
    f32x4 acc[4][4] = {};
    const int r16 = lane & 15;
    const int kg8 = (lane >> 4) * 8;
    const unsigned short* wbase = Wt + ((size_t)(wv * 64 + r16)) * 256 + kg8;
    const unsigned short* abase = Al + r16 * APAD + kg8;

#pragma unroll
    for (int k0 = 0; k0 < 256; k0 += 32) {
        bf16x8 af[4], bfr[4];
#pragma unroll
        for (int mi = 0; mi < 4; ++mi)
            af[mi] = *(const bf16x8*)&abase[mi * 16 * APAD + k0];
#pragma unroll
        for (int ni = 0; ni < 4; ++ni)
            bfr[ni] = *(const bf16x8*)&wbase[ni * 16 * 256 + k0];
#pragma unroll
        for (int mi = 0; mi < 4; ++mi)
#pragma unroll
            for (int ni = 0; ni < 4; ++ni)
                acc[mi][ni] = __builtin_amdgcn_mfma_f32_16x16x32_bf16(af[mi], bfr[ni], acc[mi][ni], 0, 0, 0);
    }

#pragma unroll
    for (int mi = 0; mi < 4; ++mi) {
        int rbase = m0 + mi * 16 + ((lane >> 4) << 2);
#pragma unroll
        for (int ni = 0; ni < 4; ++ni) {
            int col = (wv << 6) + (ni << 4) + (lane & 15);
#pragma unroll
            for (int j = 0; j < 4; ++j) {
                int row = rbase + j;
                if (row < M) out[(size_t)row * 256 + col] = f2f8(sd[row - m0] * acc[mi][ni][j]);
            }
        }
    }
}

// conv1: A fp32 -> g8; also emits feat fp8 into repfeat8[:,256:512)
__global__ __launch_bounds__(256) void gemm_mfma_f32A(const float* __restrict__ A,
                                                      const float* __restrict__ dinv,
                                                      const unsigned short* __restrict__ Wt,
                                                      unsigned char* __restrict__ out,
                                                      unsigned char* __restrict__ repfeat8, int M) {
    __shared__ unsigned short Al[64 * APAD];
    __shared__ float sd[64];
    const int tid = threadIdx.x;
    const int m0 = blockIdx.x * 64;
    if (tid < 64) sd[tid] = (m0 + tid < M) ? dinv[m0 + tid] : 0.f;
#pragma unroll
    for (int i = 0; i < 8; ++i) {
        int u = i * 256 + tid;
        int r = u >> 5;
        int c8 = (u & 31) * 8;
        int row = m0 + r;
        float4 v0, v1;
        if (row < M) {
            v0 = *(const float4*)&A[(size_t)row * 256 + c8];
            v1 = *(const float4*)&A[(size_t)row * 256 + c8 + 4];
        } else {
            v0 = make_float4(0.f, 0.f, 0.f, 0.f);
            v1 = v0;
        }
        uint4 o;
        o.x = (unsigned int)f2bf(v0.x) | ((unsigned int)f2bf(v0.y) << 16);
        o.y = (unsigned int)f2bf(v0.z) | ((unsigned int)f2bf(v0.w) << 16);
        o.z = (unsigned int)f2bf(v1.x) | ((unsigned int)f2bf(v1.y) << 16);
        o.w = (unsigned int)f2bf(v1.z) | ((unsigned int)f2bf(v1.w) << 16);
        *(uint4*)&Al[r * APAD + c8] = o;
        if (row < M) {
            int w0 = __builtin_amdgcn_cvt_pk_fp8_f32(v0.x, v0.y, 0, false);
            w0 = __builtin_amdgcn_cvt_pk_fp8_f32(v0.z, v0.w, w0, true);
            int w1 = __builtin_amdgcn_cvt_pk_fp8_f32(v1.x, v1.y, 0, false);
            w1 = __builtin_amdgcn_cvt_pk_fp8_f32(v1.z, v1.w, w1, true);
            uint2 f;
            f.x = (unsigned int)w0;
            f.y = (unsigned int)w1;
            *(uint2*)&repfeat8[(size_t)row * 512 + 256 + c8] = f;
        }
    }
    __syncthreads();
    gemm_core_f8out(Al, sd, Wt, out, m0, tid >> 6, tid & 63, M);
}

// conv2: A bf16 -> g8
__global__ __launch_bounds__(256) void gemm_mfma_b16A(const unsigned short* __restrict__ A,
                                                      const float* __restrict__ dinv,
                                                      const unsigned short* __restrict__ Wt,
                                                      unsigned char* __restrict__ out, int M) {
    __shared__ unsigned short Al[64 * APAD];
    __shared__ float sd[64];
    const int tid = threadIdx.x;
    const int m0 = blockIdx.x * 64;
    if (tid < 64) sd[tid] = (m0 + tid < M) ? dinv[m0 + tid] : 0.f;
#pragma unroll
    for (int i = 0; i < 8; ++i) {
        int u = i * 256 + tid;
        int r = u >> 5;
        int c8 = (u & 31) * 8;
        int row = m0 + r;
        uint4 o = make_uint4(0, 0, 0, 0);
        if (row < M) o = *(const uint4*)&A[(size_t)row * 256 + c8];
        *(uint4*)&Al[r * APAD + c8] = o;
    }
    __syncthreads();
    gemm_core_f8out(Al, sd, Wt, out, m0, tid >> 6, tid & 63, M);
}

// ---------------- MFMA head GEMM from fp8 rep ----------------
__global__ __launch_bounds__(256) void gemm_wy_f8A(const unsigned char* __restrict__ repfeat8,
                                                   const unsigned short* __restrict__ WyT,
                                                   const float* __restrict__ bias,
                                                   float* __restrict__ out, int M) {
    __shared__ unsigned short Al[64 * APAD];
    const int tid = threadIdx.x;
    const int m0 = blockIdx.x * 64;
    const int wv = tid >> 6;
    const int lane = tid & 63;

#pragma unroll
    for (int i = 0; i < 4; ++i) {
        int u = i * 256 + tid;
        int r = u >> 4;
        int c16 = (u & 15) * 16;
        int row = m0 + r;
        uint4 v = make_uint4(0, 0, 0, 0);
        if (row < M) v = *(const uint4*)&repfeat8[(size_t)row * 512 + c16];
        unsigned int ws[4] = {v.x, v.y, v.z, v.w};
        unsigned int ow[8];
#pragma unroll
        for (int q = 0; q < 4; ++q) {
            floatx2 lo = __builtin_amdgcn_cvt_pk_f32_fp8((int)ws[q], false);
            floatx2 hi = __builtin_amdgcn_cvt_pk_f32_fp8((int)ws[q], true);
            ow[2 * q] = (unsigned int)f2bf(lo.x) | ((unsigned int)f2bf(lo.y) << 16);
            ow[2 * q + 1] = (unsigned int)f2bf(hi.x) | ((unsigned int)f2bf(hi.y) << 16);
        }
        *(uint4*)&Al[r * APAD + c16] = make_uint4(ow[0], ow[1], ow[2], ow[3]);
        *(uint4*)&Al[r * APAD + c16 + 8] = make_uint4(ow[4], ow[5], ow[6], ow[7]);
    }
    __syncthreads();

    f32x4 acc[4] = {};
    const int r16 = lane & 15;
    const int kg8 = (lane >> 4) * 8;
    const unsigned short* wbase = WyT + ((size_t)(wv * 16 + r16)) * 256 + kg8;
    const unsigned short* abase = Al + r16 * APAD + kg8;

#pragma unroll
    for (int k0 = 0; k0 < 256; k0 += 32) {
        bf16x8 bfr = *(const bf16x8*)&wbase[k0];
#pragma unroll
        for (int mi = 0; mi < 4; ++mi) {
            bf16x8 af = *(const bf16x8*)&abase[mi * 16 * APAD + k0];
            acc[mi] = __builtin_amdgcn_mfma_f32_16x16x32_bf16(af, bfr, acc[mi], 0, 0, 0);
        }
    }

    int col = (wv << 4) + (lane & 15);
    float bv = bias[col];
#pragma unroll
    for (int mi = 0; mi < 4; ++mi) {
        int rbase = m0 + mi * 16 + ((lane >> 4) << 2);
#pragma unroll
        for (int j = 0; j < 4; ++j) {
            int row = rbase + j;
            if (row < M) out[(size_t)row * 64 + col] = acc[mi][j] + bv;
        }
    }
}

// ---------------- CSR gather SpMM: pure gather-sum; 32-lane rows ----------------
template <int DO_NORM>
__global__ __launch_bounds__(256) void spmm_gather_f8(const int* __restrict__ rowptr,
                                                      const int* __restrict__ colIdx,
                                                      const unsigned char* __restrict__ g8,
                                                      const float* __restrict__ dinv,
                                                      const float* __restrict__ bias,
                                                      unsigned short* __restrict__ out_b16,
                                                      float* __restrict__ rep,
                                                      unsigned char* __restrict__ repfeat8,
                                                      int N) {
    int row = (blockIdx.x * 256 + threadIdx.x) >> 5;
    int l = threadIdx.x & 31;
    if (row >= N) return;
    int beg = rowptr[row];
    int end = rowptr[row + 1];
    float a0 = 0.f, a1 = 0.f, a2 = 0.f, a3 = 0.f, a4 = 0.f, a5 = 0.f, a6 = 0.f, a7 = 0.f;
    int j = beg;
    for (; j + 3 < end; j += 4) {
        int cc[4];
#pragma unroll
        for (int q = 0; q < 4; ++q) cc[q] = colIdx[j + q];
        uint2 uu[4];
#pragma unroll
        for (int q = 0; q < 4; ++q) uu[q] = *(const uint2*)&g8[(size_t)cc[q] * 256 + l * 8];
#pragma unroll
        for (int q = 0; q < 4; ++q) {
            floatx2 p0 = __builtin_amdgcn_cvt_pk_f32_fp8((int)uu[q].x, false);
            floatx2 p1 = __builtin_amdgcn_cvt_pk_f32_fp8((int)uu[q].x, true);
            floatx2 p2 = __builtin_amdgcn_cvt_pk_f32_fp8((int)uu[q].y, false);
            floatx2 p3 = __builtin_amdgcn_cvt_pk_f32_fp8((int)uu[q].y, true);
            a0 += p0.x; a1 += p0.y; a2 += p1.x; a3 += p1.y;
            a4 += p2.x; a5 += p2.y; a6 += p3.x; a7 += p3.y;
        }
    }
    for (; j < end; ++j) {
        int c = colIdx[j];
        uint2 u = *(const uint2*)&g8[(size_t)c * 256 + l * 8];
        floatx2 p0 = __builtin_amdgcn_cvt_pk_f32_fp8((int)u.x, false);
        floatx2 p1 = __builtin_amdgcn_cvt_pk_f32_fp8((int)u.x, true);
        floatx2 p2 = __builtin_amdgcn_cvt_pk_f32_fp8((int)u.y, false);
        floatx2 p3 = __builtin_amdgcn_cvt_pk_f32_fp8((int)u.y, true);
        a0 += p0.x; a1 += p0.y; a2 += p1.x; a3 += p1.y;
        a4 += p2.x; a5 += p2.y; a6 += p3.x; a7 += p3.y;
    }
    float di = dinv[row];
    uint2 us = *(const uint2*)&g8[(size_t)row * 256 + l * 8];
    floatx2 s0 = __builtin_amdgcn_cvt_pk_f32_fp8((int)us.x, false);
    floatx2 s1 = __builtin_amdgcn_cvt_pk_f32_fp8((int)us.x, true);
    floatx2 s2 = __builtin_amdgcn_cvt_pk_f32_fp8((int)us.y, false);
    floatx2 s3 = __builtin_amdgcn_cvt_pk_f32_fp8((int)us.y, true);
    float4 bv0 = *(const float4*)&bias[l * 8];
    float4 bv1 = *(const float4*)&bias[l * 8 + 4];
    float r0 = fmaf(di, a0 + s0.x, bv0.x);
    float r1 = fmaf(di, a1 + s0.y, bv0.y);
    float r2 = fmaf(di, a2 + s1.x, bv0.z);
    float r3 = fmaf(di, a3 + s1.y, bv0.w);
    float r4 = fmaf(di, a4 + s2.x, bv1.x);
    float r5 = fmaf(di, a5 + s2.y, bv1.y);
    float r6 = fmaf(di, a6 + s3.x, bv1.z);
    float r7 = fmaf(di, a7 + s3.y, bv1.w);
    if (DO_NORM == 0) {
        r0 = fmaxf(r0, 0.f); r1 = fmaxf(r1, 0.f); r2 = fmaxf(r2, 0.f); r3 = fmaxf(r3, 0.f);
        r4 = fmaxf(r4, 0.f); r5 = fmaxf(r5, 0.f); r6 = fmaxf(r6, 0.f); r7 = fmaxf(r7, 0.f);
        uint4 o;
        o.x = (unsigned int)f2bf(r0) | ((unsigned int)f2bf(r1) << 16);
        o.y = (unsigned int)f2bf(r2) | ((unsigned int)f2bf(r3) << 16);
        o.z = (unsigned int)f2bf(r4) | ((unsigned int)f2bf(r5) << 16);
        o.w = (unsigned int)f2bf(r6) | ((unsigned int)f2bf(r7) << 16);
        *(uint4*)&out_b16[(size_t)row * 256 + l * 8] = o;
    } else {
        float ss = r0 * r0 + r1 * r1 + r2 * r2 + r3 * r3 + r4 * r4 + r5 * r5 + r6 * r6 + r7 * r7;
#pragma unroll
        for (int o = 1; o < 32; o <<= 1) ss += __shfl_xor(ss, o);
        float inv = 1.0f / fmaxf(sqrtf(ss), 1e-12f);
        r0 *= inv; r1 *= inv; r2 *= inv; r3 *= inv;
        r4 *= inv; r5 *= inv; r6 *= inv; r7 *= inv;
        float ss2 = r0 * r0 + r1 * r1 + r2 * r2 + r3 * r3 + r4 * r4 + r5 * r5 + r6 * r6 + r7 * r7;
#pragma unroll
        for (int o = 1; o < 32; o <<= 1) ss2 += __shfl_xor(ss2, o);
        float inv2 = 1.0f / fmaxf(sqrtf(ss2), 1e-12f);
        r0 *= inv2; r1 *= inv2; r2 *= inv2; r3 *= inv2;
        r4 *= inv2; r5 *= inv2; r6 *= inv2; r7 *= inv2;
        *(float4*)&rep[(size_t)row * 256 + l * 8] = make_float4(r0, r1, r2, r3);
        *(float4*)&rep[(size_t)row * 256 + l * 8 + 4] = make_float4(r4, r5, r6, r7);
        int w0 = __builtin_amdgcn_cvt_pk_fp8_f32(r0, r1, 0, false);
        w0 = __builtin_amdgcn_cvt_pk_fp8_f32(r2, r3, w0, true);
        int w1 = __builtin_amdgcn_cvt_pk_fp8_f32(r4, r5, 0, false);
        w1 = __builtin_amdgcn_cvt_pk_fp8_f32(r6, r7, w1, true);
        uint2 o;
        o.x = (unsigned int)w0;
        o.y = (unsigned int)w1;
        *(uint2*)&repfeat8[(size_t)row * 512 + l * 8] = o;
    }
}

// ---------------- loss helpers ----------------
__device__ __forceinline__ float dot16fp8(uint4 x, uint4 y) {
    float s = 0.f;
    const unsigned int xs[4] = {x.x, x.y, x.z, x.w};
    const unsigned int ys[4] = {y.x, y.y, y.z, y.w};
#pragma unroll
    for (int i = 0; i < 4; ++i) {
        floatx2 xl = __builtin_amdgcn_cvt_pk_f32_fp8((int)xs[i], false);
        floatx2 xh = __builtin_amdgcn_cvt_pk_f32_fp8((int)xs[i], true);
        floatx2 yl = __builtin_amdgcn_cvt_pk_f32_fp8((int)ys[i], false);
        floatx2 yh = __builtin_amdgcn_cvt_pk_f32_fp8((int)ys[i], true);
        s += xl.x * yl.x + xl.y * yl.y + xh.x * yh.x + xh.y * yh.y;
    }
    return s;
}

// ---------------- merged loss over node-bucketed lists + interleaved repfeat8 ----------------
__global__ __launch_bounds__(256) void loss_all(const int2* __restrict__ posAB,
                                                const float* __restrict__ posLS,
                                                const int2* __restrict__ negCD,
                                                const int* __restrict__ cnt,
                                                const unsigned char* __restrict__ repfeat8,
                                                float* accum) {
    const int tid = threadIdx.x;
    const int l8 = tid & 7;
    const int grp = (blockIdx.x * 256 + tid) >> 3;
    const int ngrp = gridDim.x * 32;
    const int P = cnt[0];
    const int T = P + cnt[1];
    float ap = 0.f, an = 0.f;
    for (int g = grp; g < T; g += ngrp) {
        if (g < P) {
            int2 ab = posAB[g];
            const unsigned char* pa = &repfeat8[(size_t)ab.x * 512 + l8 * 32];
            const unsigned char* pb = &repfeat8[(size_t)ab.y * 512 + l8 * 32];
            uint4 ra0 = *(const uint4*)pa;
            uint4 ra1 = *(const uint4*)(pa + 16);
            uint4 fa0 = *(const uint4*)(pa + 256);
            uint4 fa1 = *(const uint4*)(pa + 272);
            uint4 rb0 = *(const uint4*)pb;
            uint4 rb1 = *(const uint4*)(pb + 16);
            uint4 fb0 = *(const uint4*)(pb + 256);
            uint4 fb1 = *(const uint4*)(pb + 272);
            float dp = dot16fp8(ra0, rb0) + dot16fp8(ra1, rb1);
            float df = dot16fp8(fa0, fb0) + dot16fp8(fa1, fb1);
#pragma unroll
            for (int o = 1; o < 8; o <<= 1) {
                dp += __shfl_xor(dp, o);
                df += __shfl_xor(df, o);
            }
            if (l8 == 0) {
                float pw = fmaxf(dp, 0.f);
                float pos = THETA * df + (1.0f - THETA) * pw;
                float t = pos - posLS[g];
                ap += t * t;
            }
        } else {
            int2 cd = negCD[g - P];
            const unsigned char* pc = &repfeat8[(size_t)cd.x * 512 + l8 * 32];
            const unsigned char* pd = &repfeat8[(size_t)cd.y * 512 + l8 * 32];
            uint4 rc0 = *(const uint4*)pc;
            uint4 rc1 = *(const uint4*)(pc + 16);
            uint4 rd0 = *(const uint4*)pd;
            uint4 rd1 = *(const uint4*)(pd + 16);
            float dn = dot16fp8(rc0, rd0) + dot16fp8(rc1, rd1);
#pragma unroll
            for (int o = 1; o < 8; o <<= 1) dn += __shfl_xor(dn, o);
            if (l8 == 0) {
                float nwt = fmaxf(dn, 0.f);
                an += nwt * nwt;
            }
        }
    }
#pragma unroll
    for (int o = 1; o < 64; o <<= 1) {
        ap += __shfl_xor(ap, o);
        an += __shfl_xor(an, o);
    }
    __shared__ float s[4][2];
    if ((tid & 63) == 0) {
        s[tid >> 6][0] = ap;
        s[tid >> 6][1] = an;
    }
    __syncthreads();
    if (tid == 0) {
        unsafeAtomicAdd(&accum[0], s[0][0] + s[1][0] + s[2][0] + s[3][0]);
        unsafeAtomicAdd(&accum[1], s[0][1] + s[1][1] + s[2][1] + s[3][1]);
    }
}

__global__ void loss_final(const float* __restrict__ accum, const int* __restrict__ cnt,
                           float* __restrict__ out, int N) {
    out[0] = (accum[0] + accum[1]) * (float)N / (float)(cnt[0] + cnt[1]);
}

// ---------------- launcher ----------------
extern "C" void kernel_launch(void* const* d_in, const int* in_sizes, int n_in,
                              void* d_out, int out_size, void* d_ws, size_t ws_size,
                              hipStream_t stream) {
    const int* edge = (const int*)d_in[0];
    const float* features = (const float*)d_in[1];
    const float* ls = (const float*)d_in[2];
    const int* nedge = (const int*)d_in[3];
    const float* W1 = (const float*)d_in[4];
    const float* b1 = (const float*)d_in[5];
    const float* W2 = (const float*)d_in[6];
    const float* b2 = (const float*)d_in[7];
    const float* Wy = (const float*)d_in[8];
    const float* by = (const float*)d_in[9];

    const int E = in_sizes[0] / 2;
    const int N = in_sizes[1] / FEAT;
    const int* e0 = edge;
    const int* e1 = edge + E;
    const int* n0 = nedge;
    const int* n1 = nedge + E;

    float* rep = (float*)d_out;          // [N,256]
    float* rec = rep + (size_t)N * 256;  // scalar
    float* y = rec + 1;                  // [N,64], 4B-aligned only

    // workspace carve-out
    char* base = (char*)d_ws;
    size_t off = 0;
    auto carve = [&](size_t bytes) -> void* {
        void* p = base + off;
        off += (bytes + 1023) & ~(size_t)1023;
        return p;
    };
    int* deg3 = (int*)carve((size_t)3 * N * 4);  // deg | posDeg | negDeg
    float* dinv = (float*)carve((size_t)N * 4);
    float* accum = (float*)carve(16);
    int* cnt = (int*)carve(16);
    int* rowptr = (int*)carve((size_t)(N + 1) * 4);
    int* cursor = (int*)carve((size_t)N * 4);
    int* posCur = (int*)carve((size_t)N * 4);
    int* negCur = (int*)carve((size_t)N * 4);
    int* colIdx = (int*)carve((size_t)E * 4);
    unsigned char* g8 = (unsigned char*)carve((size_t)N * 256);
    unsigned short* x1B = (unsigned short*)carve((size_t)N * 256 * 2);
    unsigned char* repfeat8 = (unsigned char*)carve((size_t)N * 512);
    unsigned short* Wt1 = (unsigned short*)carve(256 * 256 * 2);
    unsigned short* Wt2 = (unsigned short*)carve(256 * 256 * 2);
    unsigned short* WyT = (unsigned short*)carve(64 * 256 * 2);
    int2* posAB = (int2*)carve((size_t)E * 8);
    float* posLS = (float*)carve((size_t)E * 4);
    int2* negCD = (int2*)carve((size_t)E * 8);
    const int nbn = (N + 255) / 256;
    int* blkS3 = (int*)carve((size_t)3 * nbn * 4);

    const int ebk = (E + 255) / 256;
    const int gblk = (N + 63) / 64;
    const int wblk32 = (N + 7) / 8;

    hipMemsetAsync(deg3, 0, (size_t)3 * N * 4, stream);
    hipMemsetAsync(accum, 0, 16, stream);

    // mega-prep: 3-way degree counts | W transposes
    prep<<<ebk + 512 + 64, 256, 0, stream>>>(e0, e1, n0, n1, deg3,
                                             W1, Wt1, W2, Wt2, Wy, WyT, E, N, ebk);

    // scan chain (3 arrays) + bucket
    scan1_dinv<<<nbn, 256, 0, stream>>>(deg3, rowptr, posCur, negCur, blkS3, dinv, N, nbn);
    scan2<<<1, 256, 0, stream>>>(blkS3, cnt, nbn);
    scan3<<<nbn, 256, 0, stream>>>(rowptr, cursor, posCur, negCur, blkS3, N, E, nbn);
    bucket_all<<<ebk, 256, 0, stream>>>(e0, e1, n0, n1, ls, cursor, posCur, negCur,
                                        colIdx, posAB, posLS, negCD, E);

    // conv1: g8 = fp8(dinv .* (features @ W1)); feat8 emitted alongside
    gemm_mfma_f32A<<<gblk, 256, 0, stream>>>(features, dinv, Wt1, g8, repfeat8, N);
    spmm_gather_f8<0><<<wblk32, 256, 0, stream>>>(rowptr, colIdx, g8, dinv, b1, x1B, nullptr, nullptr, N);

    // conv2: g8 = fp8(dinv .* (x1 @ W2)); fused gather + l2norm2 -> rep fp32 + rep8
    gemm_mfma_b16A<<<gblk, 256, 0, stream>>>(x1B, dinv, Wt2, g8, N);
    spmm_gather_f8<1><<<wblk32, 256, 0, stream>>>(rowptr, colIdx, g8, dinv, b2, nullptr, rep, repfeat8, N);

    // y = rep8 @ Wy + by
    gemm_wy_f8A<<<gblk, 256, 0, stream>>>(repfeat8, WyT, by, y, N);

    // merged loss over node-bucketed lists
    loss_all<<<2048, 256, 0, stream>>>(posAB, posLS, negCD, cnt, repfeat8, accum);
    loss_final<<<1, 1, 0, stream>>>(accum, cnt, rec, N);
}

// Round 17
// 366.829 us; speedup vs baseline: 1.2190x; 1.2190x over previous
//
#include <hip/hip_runtime.h>
#include <hip/hip_bf16.h>

#define FEAT 256
#define HDIM 256
#define CDIM 64
#define THETA 0.5f
#define APAD 264  // A-tile LDS row stride in bf16 elems

typedef float floatx2 __attribute__((ext_vector_type(2)));
typedef __attribute__((ext_vector_type(8))) short bf16x8;
typedef __attribute__((ext_vector_type(4))) float f32x4;

// ---------------- conversions ----------------
__device__ __forceinline__ unsigned short f2bf(float f) {
    unsigned int u = __float_as_uint(f);
    u += 0x7fffu + ((u >> 16) & 1u);
    return (unsigned short)(u >> 16);
}
__device__ __forceinline__ unsigned char f2f8(float f) {
    int w = __builtin_amdgcn_cvt_pk_fp8_f32(f, f, 0, false);
    return (unsigned char)(w & 0xff);
}

// ---------------- MEGA-PREP: deg_count+count_blocks | transposeW x2 | transposeWy ----------------
__global__ __launch_bounds__(256) void prep(const int* __restrict__ e0, const int* __restrict__ e1,
                                            const int* __restrict__ n0, const int* __restrict__ n1,
                                            int* deg, int* __restrict__ blkP, int* __restrict__ blkN,
                                            const float* __restrict__ W1, unsigned short* __restrict__ Wt1,
                                            const float* __restrict__ W2, unsigned short* __restrict__ Wt2,
                                            const float* __restrict__ Wy, unsigned short* __restrict__ WyT,
                                            int E, int ebk) {
    const int b = blockIdx.x;
    const int tid = threadIdx.x;
    if (b < ebk) {
        const int i = b * 256 + tid;
        const int lane = tid & 63;
        const int w = tid >> 6;
        bool vp = false, vn = false;
        if (i < E) {
            int a = e0[i], bb = e1[i];
            atomicAdd(&deg[a], 1);
            vp = a < bb;
            vn = n0[i] < n1[i];
        }
        unsigned long long mp = __ballot(vp);
        unsigned long long mn = __ballot(vn);
        __shared__ int s[8];
        if (lane == 0) {
            s[w] = __popcll(mp);
            s[4 + w] = __popcll(mn);
        }
        __syncthreads();
        if (tid == 0) blkP[b] = s[0] + s[1] + s[2] + s[3];
        if (tid == 1) blkN[b] = s[4] + s[5] + s[6] + s[7];
    } else if (b < ebk + 256) {
        int k = b - ebk;
        Wt1[(size_t)tid * 256 + k] = f2bf(W1[(size_t)k * 256 + tid]);
    } else if (b < ebk + 512) {
        int k = b - ebk - 256;
        Wt2[(size_t)tid * 256 + k] = f2bf(W2[(size_t)k * 256 + tid]);
    } else {
        int b3 = b - ebk - 512;  // 0..63
        int n = tid & 63;
        int k = b3 * 4 + (tid >> 6);
        WyT[(size_t)n * 256 + k] = f2bf(Wy[(size_t)k * 64 + n]);
    }
}

// ---------------- scan1 + dinv ----------------
__global__ __launch_bounds__(256) void scan1_dinv(const int* __restrict__ deg,
                                                  int* __restrict__ rowptr,
                                                  int* __restrict__ blkS,
                                                  float* __restrict__ dinv, int N) {
    __shared__ int sh[256];
    const int tid = threadIdx.x;
    const int i = blockIdx.x * 256 + tid;
    int v = (i < N) ? deg[i] : 0;
    if (i < N) dinv[i] = rsqrtf((float)(v + 1));
    sh[tid] = v;
    __syncthreads();
#pragma unroll
    for (int off = 1; off < 256; off <<= 1) {
        int t = (tid >= off) ? sh[tid - off] : 0;
        __syncthreads();
        sh[tid] += t;
        __syncthreads();
    }
    if (i < N) rowptr[i] = sh[tid] - v;
    if (tid == 255) blkS[blockIdx.x] = sh[255];
}

// ---------------- scan2x ----------------
__global__ __launch_bounds__(256) void scan2x(int* __restrict__ blkS, int nbn,
                                              int* __restrict__ blkP, int* __restrict__ blkN,
                                              int* __restrict__ cnt, int nb) {
    const int tid = threadIdx.x;
    if (blockIdx.x == 0) {
        __shared__ int part[256];
        const int chunk = (nbn + 255) / 256;
        const int s = tid * chunk;
        const int e = min(s + chunk, nbn);
        int sum = 0;
        for (int i = s; i < e; ++i) sum += blkS[i];
        part[tid] = sum;
        __syncthreads();
#pragma unroll
        for (int off = 1; off < 256; off <<= 1) {
            int t = (tid >= off) ? part[tid - off] : 0;
            __syncthreads();
            part[tid] += t;
            __syncthreads();
        }
        int run = part[tid] - sum;
        for (int i = s; i < e; ++i) {
            int v = blkS[i];
            blkS[i] = run;
            run += v;
        }
    } else {
        __shared__ int partP[256], partN[256];
        const int chunk = (nb + 255) / 256;
        const int s = tid * chunk;
        const int e = min(s + chunk, nb);
        int sp = 0, sn = 0;
        for (int i = s; i < e; ++i) { sp += blkP[i]; sn += blkN[i]; }
        partP[tid] = sp;
        partN[tid] = sn;
        __syncthreads();
#pragma unroll
        for (int off = 1; off < 256; off <<= 1) {
            int tp = (tid >= off) ? partP[tid - off] : 0;
            int tn = (tid >= off) ? partN[tid - off] : 0;
            __syncthreads();
            partP[tid] += tp;
            partN[tid] += tn;
            __syncthreads();
        }
        int runP = partP[tid] - sp;
        int runN = partN[tid] - sn;
        for (int i = s; i < e; ++i) {
            int vp = blkP[i], vn = blkN[i];
            blkP[i] = runP;
            blkN[i] = runN;
            runP += vp;
            runN += vn;
        }
        if (tid == 255) { cnt[0] = runP; cnt[1] = runN; }
    }
}

// ---------------- scan3 + scatter (sequential compaction writes) ----------------
__global__ __launch_bounds__(256) void scan3_scatter(int* __restrict__ rowptr, int* __restrict__ cursor,
                                                     const int* __restrict__ blkS, int N, int E, int nbn,
                                                     const int* __restrict__ e0, const int* __restrict__ e1,
                                                     const int* __restrict__ n0, const int* __restrict__ n1,
                                                     const float* __restrict__ ls,
                                                     const int* __restrict__ blkP, const int* __restrict__ blkN,
                                                     int2* __restrict__ posAB, float* __restrict__ posLS,
                                                     int2* __restrict__ negCD) {
    const int b = blockIdx.x;
    const int tid = threadIdx.x;
    if (b < nbn) {
        const int i = b * 256 + tid;
        if (i < N) {
            int v = rowptr[i] + blkS[b];
            rowptr[i] = v;
            cursor[i] = v;
        }
        if (i == 0) rowptr[N] = E;
        return;
    }
    const int eb = b - nbn;
    const int i = eb * 256 + tid;
    const int lane = tid & 63;
    const int w = tid >> 6;
    const unsigned long long below = (lane == 0) ? 0ull : ((1ull << lane) - 1ull);
    int a = 0, bb = 0, c = 0, d = 0;
    float lsv = 0.f;
    bool vp = false, vn = false;
    if (i < E) {
        a = e0[i]; bb = e1[i];
        c = n0[i]; d = n1[i];
        vp = a < bb;
        vn = c < d;
        if (vp) lsv = ls[i];
    }
    unsigned long long mp = __ballot(vp);
    unsigned long long mn = __ballot(vn);
    __shared__ int sP[4], sN[4];
    if (lane == 0) {
        sP[w] = __popcll(mp);
        sN[w] = __popcll(mn);
    }
    __syncthreads();
    int baseP = blkP[eb];
    int baseN = blkN[eb];
    for (int q = 0; q < 4; ++q) {
        if (q < w) { baseP += sP[q]; baseN += sN[q]; }
    }
    if (vp) {
        int ofs = __popcll(mp & below);
        posAB[baseP + ofs] = make_int2(a, bb);
        posLS[baseP + ofs] = lsv;
    }
    if (vn) {
        int ofs = __popcll(mn & below);
        negCD[baseN + ofs] = make_int2(c, d);
    }
}

// ---------------- bucket edges into CSR ----------------
__global__ __launch_bounds__(256) void bucket_edges(const int* __restrict__ e0,
                                                    const int* __restrict__ e1,
                                                    int* cursor, int* __restrict__ colIdx, int E) {
    int i = blockIdx.x * 256 + threadIdx.x;
    if (i < E) {
        int r = e0[i];
        int pos = atomicAdd(&cursor[r], 1);
        colIdx[pos] = e1[i];
    }
}

// ---------------- MFMA core: emits g = fp8(dinv[row] * acc) ----------------
__device__ __forceinline__ void gemm_core_f8out(const unsigned short* Al,
                                                const float* sd,
                                                const unsigned short* __restrict__ Wt,
                                                unsigned char* __restrict__ out,
                                                int m0, int wv, int lane, int M) {
    f32x4 acc[4][4] = {};
    const int r16 = lane & 15;
    const int kg8 = (lane >> 4) * 8;
    const unsigned short* wbase = Wt + ((size_t)(wv * 64 + r16)) * 256 + kg8;
    const unsigned short* abase = Al + r16 * APAD + kg8;

#pragma unroll
    for (int k0 = 0; k0 < 256; k0 += 32) {
        bf16x8 af[4], bfr[4];
#pragma unroll
        for (int mi = 0; mi < 4; ++mi)
            af[mi] = *(const bf16x8*)&abase[mi * 16 * APAD + k0];
#pragma unroll
        for (int ni = 0; ni < 4; ++ni)
            bfr[ni] = *(const bf16x8*)&wbase[ni * 16 * 256 + k0];
#pragma unroll
        for (int mi = 0; mi < 4; ++mi)
#pragma unroll
            for (int ni = 0; ni < 4; ++ni)
                acc[mi][ni] = __builtin_amdgcn_mfma_f32_16x16x32_bf16(af[mi], bfr[ni], acc[mi][ni], 0, 0, 0);
    }

#pragma unroll
    for (int mi = 0; mi < 4; ++mi) {
        int rbase = m0 + mi * 16 + ((lane >> 4) << 2);
#pragma unroll
        for (int ni = 0; ni < 4; ++ni) {
            int col = (wv << 6) + (ni << 4) + (lane & 15);
#pragma unroll
            for (int j = 0; j < 4; ++j) {
                int row = rbase + j;
                if (row < M) out[(size_t)row * 256 + col] = f2f8(sd[row - m0] * acc[mi][ni][j]);
            }
        }
    }
}

// conv1: A fp32 -> g8; also emits feat fp8 into repfeat8[:,256:512)
__global__ __launch_bounds__(256) void gemm_mfma_f32A(const float* __restrict__ A,
                                                      const float* __restrict__ dinv,
                                                      const unsigned short* __restrict__ Wt,
                                                      unsigned char* __restrict__ out,
                                                      unsigned char* __restrict__ repfeat8, int M) {
    __shared__ unsigned short Al[64 * APAD];
    __shared__ float sd[64];
    const int tid = threadIdx.x;
    const int m0 = blockIdx.x * 64;
    if (tid < 64) sd[tid] = (m0 + tid < M) ? dinv[m0 + tid] : 0.f;
#pragma unroll
    for (int i = 0; i < 8; ++i) {
        int u = i * 256 + tid;
        int r = u >> 5;
        int c8 = (u & 31) * 8;
        int row = m0 + r;
        float4 v0, v1;
        if (row < M) {
            v0 = *(const float4*)&A[(size_t)row * 256 + c8];
            v1 = *(const float4*)&A[(size_t)row * 256 + c8 + 4];
        } else {
            v0 = make_float4(0.f, 0.f, 0.f, 0.f);
            v1 = v0;
        }
        uint4 o;
        o.x = (unsigned int)f2bf(v0.x) | ((unsigned int)f2bf(v0.y) << 16);
        o.y = (unsigned int)f2bf(v0.z) | ((unsigned int)f2bf(v0.w) << 16);
        o.z = (unsigned int)f2bf(v1.x) | ((unsigned int)f2bf(v1.y) << 16);
        o.w = (unsigned int)f2bf(v1.z) | ((unsigned int)f2bf(v1.w) << 16);
        *(uint4*)&Al[r * APAD + c8] = o;
        if (row < M) {
            int w0 = __builtin_amdgcn_cvt_pk_fp8_f32(v0.x, v0.y, 0, false);
            w0 = __builtin_amdgcn_cvt_pk_fp8_f32(v0.z, v0.w, w0, true);
            int w1 = __builtin_amdgcn_cvt_pk_fp8_f32(v1.x, v1.y, 0, false);
            w1 = __builtin_amdgcn_cvt_pk_fp8_f32(v1.z, v1.w, w1, true);
            uint2 f;
            f.x = (unsigned int)w0;
            f.y = (unsigned int)w1;
            *(uint2*)&repfeat8[(size_t)row * 512 + 256 + c8] = f;
        }
    }
    __syncthreads();
    gemm_core_f8out(Al, sd, Wt, out, m0, tid >> 6, tid & 63, M);
}

// conv2: A bf16 -> g8
__global__ __launch_bounds__(256) void gemm_mfma_b16A(const unsigned short* __restrict__ A,
                                                      const float* __restrict__ dinv,
                                                      const unsigned short* __restrict__ Wt,
                                                      unsigned char* __restrict__ out, int M) {
    __shared__ unsigned short Al[64 * APAD];
    __shared__ float sd[64];
    const int tid = threadIdx.x;
    const int m0 = blockIdx.x * 64;
    if (tid < 64) sd[tid] = (m0 + tid < M) ? dinv[m0 + tid] : 0.f;
#pragma unroll
    for (int i = 0; i < 8; ++i) {
        int u = i * 256 + tid;
        int r = u >> 5;
        int c8 = (u & 31) * 8;
        int row = m0 + r;
        uint4 o = make_uint4(0, 0, 0, 0);
        if (row < M) o = *(const uint4*)&A[(size_t)row * 256 + c8];
        *(uint4*)&Al[r * APAD + c8] = o;
    }
    __syncthreads();
    gemm_core_f8out(Al, sd, Wt, out, m0, tid >> 6, tid & 63, M);
}

// ---------------- MFMA head GEMM from fp8 rep ----------------
__global__ __launch_bounds__(256) void gemm_wy_f8A(const unsigned char* __restrict__ repfeat8,
                                                   const unsigned short* __restrict__ WyT,
                                                   const float* __restrict__ bias,
                                                   float* __restrict__ out, int M) {
    __shared__ unsigned short Al[64 * APAD];
    const int tid = threadIdx.x;
    const int m0 = blockIdx.x * 64;
    const int wv = tid >> 6;
    const int lane = tid & 63;

#pragma unroll
    for (int i = 0; i < 4; ++i) {
        int u = i * 256 + tid;
        int r = u >> 4;
        int c16 = (u & 15) * 16;
        int row = m0 + r;
        uint4 v = make_uint4(0, 0, 0, 0);
        if (row < M) v = *(const uint4*)&repfeat8[(size_t)row * 512 + c16];
        unsigned int ws[4] = {v.x, v.y, v.z, v.w};
        unsigned int ow[8];
#pragma unroll
        for (int q = 0; q < 4; ++q) {
            floatx2 lo = __builtin_amdgcn_cvt_pk_f32_fp8((int)ws[q], false);
            floatx2 hi = __builtin_amdgcn_cvt_pk_f32_fp8((int)ws[q], true);
            ow[2 * q] = (unsigned int)f2bf(lo.x) | ((unsigned int)f2bf(lo.y) << 16);
            ow[2 * q + 1] = (unsigned int)f2bf(hi.x) | ((unsigned int)f2bf(hi.y) << 16);
        }
        *(uint4*)&Al[r * APAD + c16] = make_uint4(ow[0], ow[1], ow[2], ow[3]);
        *(uint4*)&Al[r * APAD + c16 + 8] = make_uint4(ow[4], ow[5], ow[6], ow[7]);
    }
    __syncthreads();

    f32x4 acc[4] = {};
    const int r16 = lane & 15;
    const int kg8 = (lane >> 4) * 8;
    const unsigned short* wbase = WyT + ((size_t)(wv * 16 + r16)) * 256 + kg8;
    const unsigned short* abase = Al + r16 * APAD + kg8;

#pragma unroll
    for (int k0 = 0; k0 < 256; k0 += 32) {
        bf16x8 bfr = *(const bf16x8*)&wbase[k0];
#pragma unroll
        for (int mi = 0; mi < 4; ++mi) {
            bf16x8 af = *(const bf16x8*)&abase[mi * 16 * APAD + k0];
            acc[mi] = __builtin_amdgcn_mfma_f32_16x16x32_bf16(af, bfr, acc[mi], 0, 0, 0);
        }
    }

    int col = (wv << 4) + (lane & 15);
    float bv = bias[col];
#pragma unroll
    for (int mi = 0; mi < 4; ++mi) {
        int rbase = m0 + mi * 16 + ((lane >> 4) << 2);
#pragma unroll
        for (int j = 0; j < 4; ++j) {
            int row = rbase + j;
            if (row < M) out[(size_t)row * 64 + col] = acc[mi][j] + bv;
        }
    }
}

// ---------------- CSR gather SpMM: pure gather-sum; 32-lane rows ----------------
template <int DO_NORM>
__global__ __launch_bounds__(256) void spmm_gather_f8(const int* __restrict__ rowptr,
                                                      const int* __restrict__ colIdx,
                                                      const unsigned char* __restrict__ g8,
                                                      const float* __restrict__ dinv,
                                                      const float* __restrict__ bias,
                                                      unsigned short* __restrict__ out_b16,
                                                      float* __restrict__ rep,
                                                      unsigned char* __restrict__ repfeat8,
                                                      int N) {
    int row = (blockIdx.x * 256 + threadIdx.x) >> 5;
    int l = threadIdx.x & 31;
    if (row >= N) return;
    int beg = rowptr[row];
    int end = rowptr[row + 1];
    float a0 = 0.f, a1 = 0.f, a2 = 0.f, a3 = 0.f, a4 = 0.f, a5 = 0.f, a6 = 0.f, a7 = 0.f;
    int j = beg;
    for (; j + 3 < end; j += 4) {
        int cc[4];
#pragma unroll
        for (int q = 0; q < 4; ++q) cc[q] = colIdx[j + q];
        uint2 uu[4];
#pragma unroll
        for (int q = 0; q < 4; ++q) uu[q] = *(const uint2*)&g8[(size_t)cc[q] * 256 + l * 8];
#pragma unroll
        for (int q = 0; q < 4; ++q) {
            floatx2 p0 = __builtin_amdgcn_cvt_pk_f32_fp8((int)uu[q].x, false);
            floatx2 p1 = __builtin_amdgcn_cvt_pk_f32_fp8((int)uu[q].x, true);
            floatx2 p2 = __builtin_amdgcn_cvt_pk_f32_fp8((int)uu[q].y, false);
            floatx2 p3 = __builtin_amdgcn_cvt_pk_f32_fp8((int)uu[q].y, true);
            a0 += p0.x; a1 += p0.y; a2 += p1.x; a3 += p1.y;
            a4 += p2.x; a5 += p2.y; a6 += p3.x; a7 += p3.y;
        }
    }
    for (; j < end; ++j) {
        int c = colIdx[j];
        uint2 u = *(const uint2*)&g8[(size_t)c * 256 + l * 8];
        floatx2 p0 = __builtin_amdgcn_cvt_pk_f32_fp8((int)u.x, false);
        floatx2 p1 = __builtin_amdgcn_cvt_pk_f32_fp8((int)u.x, true);
        floatx2 p2 = __builtin_amdgcn_cvt_pk_f32_fp8((int)u.y, false);
        floatx2 p3 = __builtin_amdgcn_cvt_pk_f32_fp8((int)u.y, true);
        a0 += p0.x; a1 += p0.y; a2 += p1.x; a3 += p1.y;
        a4 += p2.x; a5 += p2.y; a6 += p3.x; a7 += p3.y;
    }
    float di = dinv[row];
    uint2 us = *(const uint2*)&g8[(size_t)row * 256 + l * 8];
    floatx2 s0 = __builtin_amdgcn_cvt_pk_f32_fp8((int)us.x, false);
    floatx2 s1 = __builtin_amdgcn_cvt_pk_f32_fp8((int)us.x, true);
    floatx2 s2 = __builtin_amdgcn_cvt_pk_f32_fp8((int)us.y, false);
    floatx2 s3 = __builtin_amdgcn_cvt_pk_f32_fp8((int)us.y, true);
    float4 bv0 = *(const float4*)&bias[l * 8];
    float4 bv1 = *(const float4*)&bias[l * 8 + 4];
    float r0 = fmaf(di, a0 + s0.x, bv0.x);
    float r1 = fmaf(di, a1 + s0.y, bv0.y);
    float r2 = fmaf(di, a2 + s1.x, bv0.z);
    float r3 = fmaf(di, a3 + s1.y, bv0.w);
    float r4 = fmaf(di, a4 + s2.x, bv1.x);
    float r5 = fmaf(di, a5 + s2.y, bv1.y);
    float r6 = fmaf(di, a6 + s3.x, bv1.z);
    float r7 = fmaf(di, a7 + s3.y, bv1.w);
    if (DO_NORM == 0) {
        r0 = fmaxf(r0, 0.f); r1 = fmaxf(r1, 0.f); r2 = fmaxf(r2, 0.f); r3 = fmaxf(r3, 0.f);
        r4 = fmaxf(r4, 0.f); r5 = fmaxf(r5, 0.f); r6 = fmaxf(r6, 0.f); r7 = fmaxf(r7, 0.f);
        uint4 o;
        o.x = (unsigned int)f2bf(r0) | ((unsigned int)f2bf(r1) << 16);
        o.y = (unsigned int)f2bf(r2) | ((unsigned int)f2bf(r3) << 16);
        o.z = (unsigned int)f2bf(r4) | ((unsigned int)f2bf(r5) << 16);
        o.w = (unsigned int)f2bf(r6) | ((unsigned int)f2bf(r7) << 16);
        *(uint4*)&out_b16[(size_t)row * 256 + l * 8] = o;
    } else {
        float ss = r0 * r0 + r1 * r1 + r2 * r2 + r3 * r3 + r4 * r4 + r5 * r5 + r6 * r6 + r7 * r7;
#pragma unroll
        for (int o = 1; o < 32; o <<= 1) ss += __shfl_xor(ss, o);
        float inv = 1.0f / fmaxf(sqrtf(ss), 1e-12f);
        r0 *= inv; r1 *= inv; r2 *= inv; r3 *= inv;
        r4 *= inv; r5 *= inv; r6 *= inv; r7 *= inv;
        float ss2 = r0 * r0 + r1 * r1 + r2 * r2 + r3 * r3 + r4 * r4 + r5 * r5 + r6 * r6 + r7 * r7;
#pragma unroll
        for (int o = 1; o < 32; o <<= 1) ss2 += __shfl_xor(ss2, o);
        float inv2 = 1.0f / fmaxf(sqrtf(ss2), 1e-12f);
        r0 *= inv2; r1 *= inv2; r2 *= inv2; r3 *= inv2;
        r4 *= inv2; r5 *= inv2; r6 *= inv2; r7 *= inv2;
        *(float4*)&rep[(size_t)row * 256 + l * 8] = make_float4(r0, r1, r2, r3);
        *(float4*)&rep[(size_t)row * 256 + l * 8 + 4] = make_float4(r4, r5, r6, r7);
        int w0 = __builtin_amdgcn_cvt_pk_fp8_f32(r0, r1, 0, false);
        w0 = __builtin_amdgcn_cvt_pk_fp8_f32(r2, r3, w0, true);
        int w1 = __builtin_amdgcn_cvt_pk_fp8_f32(r4, r5, 0, false);
        w1 = __builtin_amdgcn_cvt_pk_fp8_f32(r6, r7, w1, true);
        uint2 o;
        o.x = (unsigned int)w0;
        o.y = (unsigned int)w1;
        *(uint2*)&repfeat8[(size_t)row * 512 + l * 8] = o;
    }
}

// ---------------- loss helpers ----------------
__device__ __forceinline__ float dot16fp8(uint4 x, uint4 y) {
    float s = 0.f;
    const unsigned int xs[4] = {x.x, x.y, x.z, x.w};
    const unsigned int ys[4] = {y.x, y.y, y.z, y.w};
#pragma unroll
    for (int i = 0; i < 4; ++i) {
        floatx2 xl = __builtin_amdgcn_cvt_pk_f32_fp8((int)xs[i], false);
        floatx2 xh = __builtin_amdgcn_cvt_pk_f32_fp8((int)xs[i], true);
        floatx2 yl = __builtin_amdgcn_cvt_pk_f32_fp8((int)ys[i], false);
        floatx2 yh = __builtin_amdgcn_cvt_pk_f32_fp8((int)ys[i], true);
        s += xl.x * yl.x + xl.y * yl.y + xh.x * yh.x + xh.y * yh.y;
    }
    return s;
}

// ---------------- pos loss: one pos edge per 8-lane group over repfeat8 ----------------
__global__ __launch_bounds__(256) void loss_pos(const int2* __restrict__ posAB,
                                                const float* __restrict__ posLS,
                                                const int* __restrict__ cnt,
                                                const unsigned char* __restrict__ repfeat8,
                                                float* accum) {
    const int tid = threadIdx.x;
    const int l8 = tid & 7;
    const int grp = (blockIdx.x * 256 + tid) >> 3;
    const int ngrp = gridDim.x * 32;
    const int P = cnt[0];
    float ap = 0.f;
    for (int g = grp; g < P; g += ngrp) {
        int2 ab = posAB[g];
        const unsigned char* pa = &repfeat8[(size_t)ab.x * 512 + l8 * 32];
        const unsigned char* pb = &repfeat8[(size_t)ab.y * 512 + l8 * 32];
        uint4 ra0 = *(const uint4*)pa;
        uint4 ra1 = *(const uint4*)(pa + 16);
        uint4 fa0 = *(const uint4*)(pa + 256);
        uint4 fa1 = *(const uint4*)(pa + 272);
        uint4 rb0 = *(const uint4*)pb;
        uint4 rb1 = *(const uint4*)(pb + 16);
        uint4 fb0 = *(const uint4*)(pb + 256);
        uint4 fb1 = *(const uint4*)(pb + 272);
        float dp = dot16fp8(ra0, rb0) + dot16fp8(ra1, rb1);
        float df = dot16fp8(fa0, fb0) + dot16fp8(fa1, fb1);
#pragma unroll
        for (int o = 1; o < 8; o <<= 1) {
            dp += __shfl_xor(dp, o);
            df += __shfl_xor(df, o);
        }
        if (l8 == 0) {
            float pw = fmaxf(dp, 0.f);
            float pos = THETA * df + (1.0f - THETA) * pw;
            float t = pos - posLS[g];
            ap += t * t;
        }
    }
#pragma unroll
    for (int o = 1; o < 64; o <<= 1) ap += __shfl_xor(ap, o);
    __shared__ float s[4];
    if ((tid & 63) == 0) s[tid >> 6] = ap;
    __syncthreads();
    if (tid == 0) unsafeAtomicAdd(&accum[0], s[0] + s[1] + s[2] + s[3]);
}

// ---------------- neg loss: one neg edge per 8-lane group (rep half only) ----------------
__global__ __launch_bounds__(256) void loss_neg(const int2* __restrict__ negCD,
                                                const int* __restrict__ cnt,
                                                const unsigned char* __restrict__ repfeat8,
                                                float* accum) {
    const int tid = threadIdx.x;
    const int l8 = tid & 7;
    const int grp = (blockIdx.x * 256 + tid) >> 3;
    const int ngrp = gridDim.x * 32;
    const int Q = cnt[1];
    float an = 0.f;
    for (int g = grp; g < Q; g += ngrp) {
        int2 cd = negCD[g];
        const unsigned char* pc = &repfeat8[(size_t)cd.x * 512 + l8 * 32];
        const unsigned char* pd = &repfeat8[(size_t)cd.y * 512 + l8 * 32];
        uint4 rc0 = *(const uint4*)pc;
        uint4 rc1 = *(const uint4*)(pc + 16);
        uint4 rd0 = *(const uint4*)pd;
        uint4 rd1 = *(const uint4*)(pd + 16);
        float dn = dot16fp8(rc0, rd0) + dot16fp8(rc1, rd1);
#pragma unroll
        for (int o = 1; o < 8; o <<= 1) dn += __shfl_xor(dn, o);
        if (l8 == 0) {
            float nwt = fmaxf(dn, 0.f);
            an += nwt * nwt;
        }
    }
#pragma unroll
    for (int o = 1; o < 64; o <<= 1) an += __shfl_xor(an, o);
    __shared__ float s[4];
    if ((tid & 63) == 0) s[tid >> 6] = an;
    __syncthreads();
    if (tid == 0) unsafeAtomicAdd(&accum[1], s[0] + s[1] + s[2] + s[3]);
}

__global__ void loss_final(const float* __restrict__ accum, const int* __restrict__ cnt,
                           float* __restrict__ out, int N) {
    out[0] = (accum[0] + accum[1]) * (float)N / (float)(cnt[0] + cnt[1]);
}

// ---------------- launcher ----------------
extern "C" void kernel_launch(void* const* d_in, const int* in_sizes, int n_in,
                              void* d_out, int out_size, void* d_ws, size_t ws_size,
                              hipStream_t stream) {
    const int* edge = (const int*)d_in[0];
    const float* features = (const float*)d_in[1];
    const float* ls = (const float*)d_in[2];
    const int* nedge = (const int*)d_in[3];
    const float* W1 = (const float*)d_in[4];
    const float* b1 = (const float*)d_in[5];
    const float* W2 = (const float*)d_in[6];
    const float* b2 = (const float*)d_in[7];
    const float* Wy = (const float*)d_in[8];
    const float* by = (const float*)d_in[9];

    const int E = in_sizes[0] / 2;
    const int N = in_sizes[1] / FEAT;
    const int* e0 = edge;
    const int* e1 = edge + E;
    const int* n0 = nedge;
    const int* n1 = nedge + E;

    float* rep = (float*)d_out;          // [N,256]
    float* rec = rep + (size_t)N * 256;  // scalar
    float* y = rec + 1;                  // [N,64], 4B-aligned only

    // workspace carve-out
    char* base = (char*)d_ws;
    size_t off = 0;
    auto carve = [&](size_t bytes) -> void* {
        void* p = base + off;
        off += (bytes + 1023) & ~(size_t)1023;
        return p;
    };
    int* deg = (int*)carve((size_t)N * 4);
    float* dinv = (float*)carve((size_t)N * 4);
    float* accum = (float*)carve(16);
    int* cnt = (int*)carve(16);
    int* rowptr = (int*)carve((size_t)(N + 1) * 4);
    int* cursor = (int*)carve((size_t)N * 4);
    int* colIdx = (int*)carve((size_t)E * 4);
    unsigned char* g8 = (unsigned char*)carve((size_t)N * 256);
    unsigned short* x1B = (unsigned short*)carve((size_t)N * 256 * 2);
    unsigned char* repfeat8 = (unsigned char*)carve((size_t)N * 512);
    unsigned short* Wt1 = (unsigned short*)carve(256 * 256 * 2);
    unsigned short* Wt2 = (unsigned short*)carve(256 * 256 * 2);
    unsigned short* WyT = (unsigned short*)carve(64 * 256 * 2);
    int2* posAB = (int2*)carve((size_t)E * 8);
    float* posLS = (float*)carve((size_t)E * 4);
    int2* negCD = (int2*)carve((size_t)E * 8);
    const int ebk = (E + 255) / 256;
    int* blkP = (int*)carve((size_t)ebk * 4);
    int* blkN = (int*)carve((size_t)ebk * 4);
    const int nbn = (N + 255) / 256;
    int* blkS = (int*)carve((size_t)nbn * 4);

    const int gblk = (N + 63) / 64;
    const int wblk32 = (N + 7) / 8;

    hipMemsetAsync(deg, 0, (size_t)N * 4, stream);
    hipMemsetAsync(accum, 0, 16, stream);

    // mega-prep: deg+counts | W transposes
    prep<<<ebk + 512 + 64, 256, 0, stream>>>(e0, e1, n0, n1, deg, blkP, blkN,
                                             W1, Wt1, W2, Wt2, Wy, WyT, E, ebk);

    // CSR scan chain + edge compaction (sequential writes)
    scan1_dinv<<<nbn, 256, 0, stream>>>(deg, rowptr, blkS, dinv, N);
    scan2x<<<2, 256, 0, stream>>>(blkS, nbn, blkP, blkN, cnt, ebk);
    scan3_scatter<<<nbn + ebk, 256, 0, stream>>>(rowptr, cursor, blkS, N, E, nbn,
                                                 e0, e1, n0, n1, ls, blkP, blkN, posAB, posLS, negCD);
    bucket_edges<<<ebk, 256, 0, stream>>>(e0, e1, cursor, colIdx, E);

    // conv1: g8 = fp8(dinv .* (features @ W1)); feat8 emitted alongside
    gemm_mfma_f32A<<<gblk, 256, 0, stream>>>(features, dinv, Wt1, g8, repfeat8, N);
    spmm_gather_f8<0><<<wblk32, 256, 0, stream>>>(rowptr, colIdx, g8, dinv, b1, x1B, nullptr, nullptr, N);

    // conv2: g8 = fp8(dinv .* (x1 @ W2)); fused gather + l2norm2 -> rep fp32 + rep8
    gemm_mfma_b16A<<<gblk, 256, 0, stream>>>(x1B, dinv, Wt2, g8, N);
    spmm_gather_f8<1><<<wblk32, 256, 0, stream>>>(rowptr, colIdx, g8, dinv, b2, nullptr, rep, repfeat8, N);

    // y = rep8 @ Wy + by
    gemm_wy_f8A<<<gblk, 256, 0, stream>>>(repfeat8, WyT, by, y, N);

    // split loss over interleaved table
    loss_pos<<<2048, 256, 0, stream>>>(posAB, posLS, cnt, repfeat8, accum);
    loss_neg<<<2048, 256, 0, stream>>>(negCD, cnt, repfeat8, accum);
    loss_final<<<1, 1, 0, stream>>>(accum, cnt, rec, N);
}

// Round 18
// 342.239 us; speedup vs baseline: 1.3066x; 1.0719x over previous
//
#include <hip/hip_runtime.h>
#include <hip/hip_bf16.h>

#define FEAT 256
#define HDIM 256
#define CDIM 64
#define THETA 0.5f
#define APAD 264  // A-tile LDS row stride in bf16 elems
#define POSBLK 1360
#define NEGBLK 688

typedef float floatx2 __attribute__((ext_vector_type(2)));
typedef __attribute__((ext_vector_type(8))) short bf16x8;
typedef __attribute__((ext_vector_type(4))) float f32x4;

// ---------------- conversions ----------------
__device__ __forceinline__ unsigned short f2bf(float f) {
    unsigned int u = __float_as_uint(f);
    u += 0x7fffu + ((u >> 16) & 1u);
    return (unsigned short)(u >> 16);
}
__device__ __forceinline__ unsigned char f2f8(float f) {
    int w = __builtin_amdgcn_cvt_pk_fp8_f32(f, f, 0, false);
    return (unsigned char)(w & 0xff);
}

// ---------------- MEGA-PREP: deg_count+count_blocks | transposeW x2 | transposeWy ----------------
__global__ __launch_bounds__(256) void prep(const int* __restrict__ e0, const int* __restrict__ e1,
                                            const int* __restrict__ n0, const int* __restrict__ n1,
                                            int* deg, int* __restrict__ blkP, int* __restrict__ blkN,
                                            const float* __restrict__ W1, unsigned short* __restrict__ Wt1,
                                            const float* __restrict__ W2, unsigned short* __restrict__ Wt2,
                                            const float* __restrict__ Wy, unsigned short* __restrict__ WyT,
                                            int E, int ebk) {
    const int b = blockIdx.x;
    const int tid = threadIdx.x;
    if (b < ebk) {
        const int i = b * 256 + tid;
        const int lane = tid & 63;
        const int w = tid >> 6;
        bool vp = false, vn = false;
        if (i < E) {
            int a = e0[i], bb = e1[i];
            atomicAdd(&deg[a], 1);
            vp = a < bb;
            vn = n0[i] < n1[i];
        }
        unsigned long long mp = __ballot(vp);
        unsigned long long mn = __ballot(vn);
        __shared__ int s[8];
        if (lane == 0) {
            s[w] = __popcll(mp);
            s[4 + w] = __popcll(mn);
        }
        __syncthreads();
        if (tid == 0) blkP[b] = s[0] + s[1] + s[2] + s[3];
        if (tid == 1) blkN[b] = s[4] + s[5] + s[6] + s[7];
    } else if (b < ebk + 256) {
        int k = b - ebk;
        Wt1[(size_t)tid * 256 + k] = f2bf(W1[(size_t)k * 256 + tid]);
    } else if (b < ebk + 512) {
        int k = b - ebk - 256;
        Wt2[(size_t)tid * 256 + k] = f2bf(W2[(size_t)k * 256 + tid]);
    } else {
        int b3 = b - ebk - 512;  // 0..63
        int n = tid & 63;
        int k = b3 * 4 + (tid >> 6);
        WyT[(size_t)n * 256 + k] = f2bf(Wy[(size_t)k * 64 + n]);
    }
}

// ---------------- scan1 + dinv ----------------
__global__ __launch_bounds__(256) void scan1_dinv(const int* __restrict__ deg,
                                                  int* __restrict__ rowptr,
                                                  int* __restrict__ blkS,
                                                  float* __restrict__ dinv, int N) {
    __shared__ int sh[256];
    const int tid = threadIdx.x;
    const int i = blockIdx.x * 256 + tid;
    int v = (i < N) ? deg[i] : 0;
    if (i < N) dinv[i] = rsqrtf((float)(v + 1));
    sh[tid] = v;
    __syncthreads();
#pragma unroll
    for (int off = 1; off < 256; off <<= 1) {
        int t = (tid >= off) ? sh[tid - off] : 0;
        __syncthreads();
        sh[tid] += t;
        __syncthreads();
    }
    if (i < N) rowptr[i] = sh[tid] - v;
    if (tid == 255) blkS[blockIdx.x] = sh[255];
}

// ---------------- scan2x ----------------
__global__ __launch_bounds__(256) void scan2x(int* __restrict__ blkS, int nbn,
                                              int* __restrict__ blkP, int* __restrict__ blkN,
                                              int* __restrict__ cnt, int nb) {
    const int tid = threadIdx.x;
    if (blockIdx.x == 0) {
        __shared__ int part[256];
        const int chunk = (nbn + 255) / 256;
        const int s = tid * chunk;
        const int e = min(s + chunk, nbn);
        int sum = 0;
        for (int i = s; i < e; ++i) sum += blkS[i];
        part[tid] = sum;
        __syncthreads();
#pragma unroll
        for (int off = 1; off < 256; off <<= 1) {
            int t = (tid >= off) ? part[tid - off] : 0;
            __syncthreads();
            part[tid] += t;
            __syncthreads();
        }
        int run = part[tid] - sum;
        for (int i = s; i < e; ++i) {
            int v = blkS[i];
            blkS[i] = run;
            run += v;
        }
    } else {
        __shared__ int partP[256], partN[256];
        const int chunk = (nb + 255) / 256;
        const int s = tid * chunk;
        const int e = min(s + chunk, nb);
        int sp = 0, sn = 0;
        for (int i = s; i < e; ++i) { sp += blkP[i]; sn += blkN[i]; }
        partP[tid] = sp;
        partN[tid] = sn;
        __syncthreads();
#pragma unroll
        for (int off = 1; off < 256; off <<= 1) {
            int tp = (tid >= off) ? partP[tid - off] : 0;
            int tn = (tid >= off) ? partN[tid - off] : 0;
            __syncthreads();
            partP[tid] += tp;
            partN[tid] += tn;
            __syncthreads();
        }
        int runP = partP[tid] - sp;
        int runN = partN[tid] - sn;
        for (int i = s; i < e; ++i) {
            int vp = blkP[i], vn = blkN[i];
            blkP[i] = runP;
            blkN[i] = runN;
            runP += vp;
            runN += vn;
        }
        if (tid == 255) { cnt[0] = runP; cnt[1] = runN; }
    }
}

// ---------------- scan3 + scatter (sequential compaction writes) ----------------
__global__ __launch_bounds__(256) void scan3_scatter(int* __restrict__ rowptr, int* __restrict__ cursor,
                                                     const int* __restrict__ blkS, int N, int E, int nbn,
                                                     const int* __restrict__ e0, const int* __restrict__ e1,
                                                     const int* __restrict__ n0, const int* __restrict__ n1,
                                                     const float* __restrict__ ls,
                                                     const int* __restrict__ blkP, const int* __restrict__ blkN,
                                                     int2* __restrict__ posAB, float* __restrict__ posLS,
                                                     int2* __restrict__ negCD) {
    const int b = blockIdx.x;
    const int tid = threadIdx.x;
    if (b < nbn) {
        const int i = b * 256 + tid;
        if (i < N) {
            int v = rowptr[i] + blkS[b];
            rowptr[i] = v;
            cursor[i] = v;
        }
        if (i == 0) rowptr[N] = E;
        return;
    }
    const int eb = b - nbn;
    const int i = eb * 256 + tid;
    const int lane = tid & 63;
    const int w = tid >> 6;
    const unsigned long long below = (lane == 0) ? 0ull : ((1ull << lane) - 1ull);
    int a = 0, bb = 0, c = 0, d = 0;
    float lsv = 0.f;
    bool vp = false, vn = false;
    if (i < E) {
        a = e0[i]; bb = e1[i];
        c = n0[i]; d = n1[i];
        vp = a < bb;
        vn = c < d;
        if (vp) lsv = ls[i];
    }
    unsigned long long mp = __ballot(vp);
    unsigned long long mn = __ballot(vn);
    __shared__ int sP[4], sN[4];
    if (lane == 0) {
        sP[w] = __popcll(mp);
        sN[w] = __popcll(mn);
    }
    __syncthreads();
    int baseP = blkP[eb];
    int baseN = blkN[eb];
    for (int q = 0; q < 4; ++q) {
        if (q < w) { baseP += sP[q]; baseN += sN[q]; }
    }
    if (vp) {
        int ofs = __popcll(mp & below);
        posAB[baseP + ofs] = make_int2(a, bb);
        posLS[baseP + ofs] = lsv;
    }
    if (vn) {
        int ofs = __popcll(mn & below);
        negCD[baseN + ofs] = make_int2(c, d);
    }
}

// ---------------- bucket edges into CSR ----------------
__global__ __launch_bounds__(256) void bucket_edges(const int* __restrict__ e0,
                                                    const int* __restrict__ e1,
                                                    int* cursor, int* __restrict__ colIdx, int E) {
    int i = blockIdx.x * 256 + threadIdx.x;
    if (i < E) {
        int r = e0[i];
        int pos = atomicAdd(&cursor[r], 1);
        colIdx[pos] = e1[i];
    }
}

// ---------------- MFMA core: emits g = fp8(dinv[row] * acc) ----------------
__device__ __forceinline__ void gemm_core_f8out(const unsigned short* Al,
                                                const float* sd,
                                                const unsigned short* __restrict__ Wt,
                                                unsigned char* __restrict__ out,
                                                int m0, int wv, int lane, int M) {
    f32x4 acc[4][4] = {};
    const int r16 = lane & 15;
    const int kg8 = (lane >> 4) * 8;
    const unsigned short* wbase = Wt + ((size_t)(wv * 64 + r16)) * 256 + kg8;
    const unsigned short* abase = Al + r16 * APAD + kg8;

#pragma unroll
    for (int k0 = 0; k0 < 256; k0 += 32) {
        bf16x8 af[4], bfr[4];
#pragma unroll
        for (int mi = 0; mi < 4; ++mi)
            af[mi] = *(const bf16x8*)&abase[mi * 16 * APAD + k0];
#pragma unroll
        for (int ni = 0; ni < 4; ++ni)
            bfr[ni] = *(const bf16x8*)&wbase[ni * 16 * 256 + k0];
#pragma unroll
        for (int mi = 0; mi < 4; ++mi)
#pragma unroll
            for (int ni = 0; ni < 4; ++ni)
                acc[mi][ni] = __builtin_amdgcn_mfma_f32_16x16x32_bf16(af[mi], bfr[ni], acc[mi][ni], 0, 0, 0);
    }

#pragma unroll
    for (int mi = 0; mi < 4; ++mi) {
        int rbase = m0 + mi * 16 + ((lane >> 4) << 2);
#pragma unroll
        for (int ni = 0; ni < 4; ++ni) {
            int col = (wv << 6) + (ni << 4) + (lane & 15);
#pragma unroll
            for (int j = 0; j < 4; ++j) {
                int row = rbase + j;
                if (row < M) out[(size_t)row * 256 + col] = f2f8(sd[row - m0] * acc[mi][ni][j]);
            }
        }
    }
}

// conv1: A fp32 -> g8; also emits feat fp8 into repfeat8[:,256:512)
__global__ __launch_bounds__(256) void gemm_mfma_f32A(const float* __restrict__ A,
                                                      const float* __restrict__ dinv,
                                                      const unsigned short* __restrict__ Wt,
                                                      unsigned char* __restrict__ out,
                                                      unsigned char* __restrict__ repfeat8, int M) {
    __shared__ unsigned short Al[64 * APAD];
    __shared__ float sd[64];
    const int tid = threadIdx.x;
    const int m0 = blockIdx.x * 64;
    if (tid < 64) sd[tid] = (m0 + tid < M) ? dinv[m0 + tid] : 0.f;
#pragma unroll
    for (int i = 0; i < 8; ++i) {
        int u = i * 256 + tid;
        int r = u >> 5;
        int c8 = (u & 31) * 8;
        int row = m0 + r;
        float4 v0, v1;
        if (row < M) {
            v0 = *(const float4*)&A[(size_t)row * 256 + c8];
            v1 = *(const float4*)&A[(size_t)row * 256 + c8 + 4];
        } else {
            v0 = make_float4(0.f, 0.f, 0.f, 0.f);
            v1 = v0;
        }
        uint4 o;
        o.x = (unsigned int)f2bf(v0.x) | ((unsigned int)f2bf(v0.y) << 16);
        o.y = (unsigned int)f2bf(v0.z) | ((unsigned int)f2bf(v0.w) << 16);
        o.z = (unsigned int)f2bf(v1.x) | ((unsigned int)f2bf(v1.y) << 16);
        o.w = (unsigned int)f2bf(v1.z) | ((unsigned int)f2bf(v1.w) << 16);
        *(uint4*)&Al[r * APAD + c8] = o;
        if (row < M) {
            int w0 = __builtin_amdgcn_cvt_pk_fp8_f32(v0.x, v0.y, 0, false);
            w0 = __builtin_amdgcn_cvt_pk_fp8_f32(v0.z, v0.w, w0, true);
            int w1 = __builtin_amdgcn_cvt_pk_fp8_f32(v1.x, v1.y, 0, false);
            w1 = __builtin_amdgcn_cvt_pk_fp8_f32(v1.z, v1.w, w1, true);
            uint2 f;
            f.x = (unsigned int)w0;
            f.y = (unsigned int)w1;
            *(uint2*)&repfeat8[(size_t)row * 512 + 256 + c8] = f;
        }
    }
    __syncthreads();
    gemm_core_f8out(Al, sd, Wt, out, m0, tid >> 6, tid & 63, M);
}

// conv2: A fp8 (x1 table, 256B records) -> g8
__global__ __launch_bounds__(256) void gemm_mfma_f8A(const unsigned char* __restrict__ A8,
                                                     const float* __restrict__ dinv,
                                                     const unsigned short* __restrict__ Wt,
                                                     unsigned char* __restrict__ out, int M) {
    __shared__ unsigned short Al[64 * APAD];
    __shared__ float sd[64];
    const int tid = threadIdx.x;
    const int m0 = blockIdx.x * 64;
    if (tid < 64) sd[tid] = (m0 + tid < M) ? dinv[m0 + tid] : 0.f;
#pragma unroll
    for (int i = 0; i < 4; ++i) {
        int u = i * 256 + tid;
        int r = u >> 4;
        int c16 = (u & 15) * 16;
        int row = m0 + r;
        uint4 v = make_uint4(0, 0, 0, 0);
        if (row < M) v = *(const uint4*)&A8[(size_t)row * 256 + c16];
        unsigned int ws[4] = {v.x, v.y, v.z, v.w};
        unsigned int ow[8];
#pragma unroll
        for (int q = 0; q < 4; ++q) {
            floatx2 lo = __builtin_amdgcn_cvt_pk_f32_fp8((int)ws[q], false);
            floatx2 hi = __builtin_amdgcn_cvt_pk_f32_fp8((int)ws[q], true);
            ow[2 * q] = (unsigned int)f2bf(lo.x) | ((unsigned int)f2bf(lo.y) << 16);
            ow[2 * q + 1] = (unsigned int)f2bf(hi.x) | ((unsigned int)f2bf(hi.y) << 16);
        }
        *(uint4*)&Al[r * APAD + c16] = make_uint4(ow[0], ow[1], ow[2], ow[3]);
        *(uint4*)&Al[r * APAD + c16 + 8] = make_uint4(ow[4], ow[5], ow[6], ow[7]);
    }
    __syncthreads();
    gemm_core_f8out(Al, sd, Wt, out, m0, tid >> 6, tid & 63, M);
}

// ---------------- MFMA head GEMM from fp8 rep ----------------
__global__ __launch_bounds__(256) void gemm_wy_f8A(const unsigned char* __restrict__ repfeat8,
                                                   const unsigned short* __restrict__ WyT,
                                                   const float* __restrict__ bias,
                                                   float* __restrict__ out, int M) {
    __shared__ unsigned short Al[64 * APAD];
    const int tid = threadIdx.x;
    const int m0 = blockIdx.x * 64;
    const int wv = tid >> 6;
    const int lane = tid & 63;

#pragma unroll
    for (int i = 0; i < 4; ++i) {
        int u = i * 256 + tid;
        int r = u >> 4;
        int c16 = (u & 15) * 16;
        int row = m0 + r;
        uint4 v = make_uint4(0, 0, 0, 0);
        if (row < M) v = *(const uint4*)&repfeat8[(size_t)row * 512 + c16];
        unsigned int ws[4] = {v.x, v.y, v.z, v.w};
        unsigned int ow[8];
#pragma unroll
        for (int q = 0; q < 4; ++q) {
            floatx2 lo = __builtin_amdgcn_cvt_pk_f32_fp8((int)ws[q], false);
            floatx2 hi = __builtin_amdgcn_cvt_pk_f32_fp8((int)ws[q], true);
            ow[2 * q] = (unsigned int)f2bf(lo.x) | ((unsigned int)f2bf(lo.y) << 16);
            ow[2 * q + 1] = (unsigned int)f2bf(hi.x) | ((unsigned int)f2bf(hi.y) << 16);
        }
        *(uint4*)&Al[r * APAD + c16] = make_uint4(ow[0], ow[1], ow[2], ow[3]);
        *(uint4*)&Al[r * APAD + c16 + 8] = make_uint4(ow[4], ow[5], ow[6], ow[7]);
    }
    __syncthreads();

    f32x4 acc[4] = {};
    const int r16 = lane & 15;
    const int kg8 = (lane >> 4) * 8;
    const unsigned short* wbase = WyT + ((size_t)(wv * 16 + r16)) * 256 + kg8;
    const unsigned short* abase = Al + r16 * APAD + kg8;

#pragma unroll
    for (int k0 = 0; k0 < 256; k0 += 32) {
        bf16x8 bfr = *(const bf16x8*)&wbase[k0];
#pragma unroll
        for (int mi = 0; mi < 4; ++mi) {
            bf16x8 af = *(const bf16x8*)&abase[mi * 16 * APAD + k0];
            acc[mi] = __builtin_amdgcn_mfma_f32_16x16x32_bf16(af, bfr, acc[mi], 0, 0, 0);
        }
    }

    int col = (wv << 4) + (lane & 15);
    float bv = bias[col];
#pragma unroll
    for (int mi = 0; mi < 4; ++mi) {
        int rbase = m0 + mi * 16 + ((lane >> 4) << 2);
#pragma unroll
        for (int j = 0; j < 4; ++j) {
            int row = rbase + j;
            if (row < M) out[(size_t)row * 64 + col] = acc[mi][j] + bv;
        }
    }
}

// ---------------- CSR gather SpMM: pure gather-sum; 32-lane rows ----------------
// DO_NORM=0: x1 fp8 out (relu)
// DO_NORM=1: double-l2norm; rep fp32 + rep fp8 -> repfeat8[:,0:256)
template <int DO_NORM>
__global__ __launch_bounds__(256) void spmm_gather_f8(const int* __restrict__ rowptr,
                                                      const int* __restrict__ colIdx,
                                                      const unsigned char* __restrict__ g8,
                                                      const float* __restrict__ dinv,
                                                      const float* __restrict__ bias,
                                                      unsigned char* __restrict__ out_f8,
                                                      float* __restrict__ rep,
                                                      unsigned char* __restrict__ repfeat8,
                                                      int N) {
    int row = (blockIdx.x * 256 + threadIdx.x) >> 5;
    int l = threadIdx.x & 31;
    if (row >= N) return;
    int beg = rowptr[row];
    int end = rowptr[row + 1];
    float a0 = 0.f, a1 = 0.f, a2 = 0.f, a3 = 0.f, a4 = 0.f, a5 = 0.f, a6 = 0.f, a7 = 0.f;
    int j = beg;
    for (; j + 3 < end; j += 4) {
        int cc[4];
#pragma unroll
        for (int q = 0; q < 4; ++q) cc[q] = colIdx[j + q];
        uint2 uu[4];
#pragma unroll
        for (int q = 0; q < 4; ++q) uu[q] = *(const uint2*)&g8[(size_t)cc[q] * 256 + l * 8];
#pragma unroll
        for (int q = 0; q < 4; ++q) {
            floatx2 p0 = __builtin_amdgcn_cvt_pk_f32_fp8((int)uu[q].x, false);
            floatx2 p1 = __builtin_amdgcn_cvt_pk_f32_fp8((int)uu[q].x, true);
            floatx2 p2 = __builtin_amdgcn_cvt_pk_f32_fp8((int)uu[q].y, false);
            floatx2 p3 = __builtin_amdgcn_cvt_pk_f32_fp8((int)uu[q].y, true);
            a0 += p0.x; a1 += p0.y; a2 += p1.x; a3 += p1.y;
            a4 += p2.x; a5 += p2.y; a6 += p3.x; a7 += p3.y;
        }
    }
    for (; j < end; ++j) {
        int c = colIdx[j];
        uint2 u = *(const uint2*)&g8[(size_t)c * 256 + l * 8];
        floatx2 p0 = __builtin_amdgcn_cvt_pk_f32_fp8((int)u.x, false);
        floatx2 p1 = __builtin_amdgcn_cvt_pk_f32_fp8((int)u.x, true);
        floatx2 p2 = __builtin_amdgcn_cvt_pk_f32_fp8((int)u.y, false);
        floatx2 p3 = __builtin_amdgcn_cvt_pk_f32_fp8((int)u.y, true);
        a0 += p0.x; a1 += p0.y; a2 += p1.x; a3 += p1.y;
        a4 += p2.x; a5 += p2.y; a6 += p3.x; a7 += p3.y;
    }
    float di = dinv[row];
    uint2 us = *(const uint2*)&g8[(size_t)row * 256 + l * 8];
    floatx2 s0 = __builtin_amdgcn_cvt_pk_f32_fp8((int)us.x, false);
    floatx2 s1 = __builtin_amdgcn_cvt_pk_f32_fp8((int)us.x, true);
    floatx2 s2 = __builtin_amdgcn_cvt_pk_f32_fp8((int)us.y, false);
    floatx2 s3 = __builtin_amdgcn_cvt_pk_f32_fp8((int)us.y, true);
    float4 bv0 = *(const float4*)&bias[l * 8];
    float4 bv1 = *(const float4*)&bias[l * 8 + 4];
    float r0 = fmaf(di, a0 + s0.x, bv0.x);
    float r1 = fmaf(di, a1 + s0.y, bv0.y);
    float r2 = fmaf(di, a2 + s1.x, bv0.z);
    float r3 = fmaf(di, a3 + s1.y, bv0.w);
    float r4 = fmaf(di, a4 + s2.x, bv1.x);
    float r5 = fmaf(di, a5 + s2.y, bv1.y);
    float r6 = fmaf(di, a6 + s3.x, bv1.z);
    float r7 = fmaf(di, a7 + s3.y, bv1.w);
    if (DO_NORM == 0) {
        r0 = fmaxf(r0, 0.f); r1 = fmaxf(r1, 0.f); r2 = fmaxf(r2, 0.f); r3 = fmaxf(r3, 0.f);
        r4 = fmaxf(r4, 0.f); r5 = fmaxf(r5, 0.f); r6 = fmaxf(r6, 0.f); r7 = fmaxf(r7, 0.f);
        int w0 = __builtin_amdgcn_cvt_pk_fp8_f32(r0, r1, 0, false);
        w0 = __builtin_amdgcn_cvt_pk_fp8_f32(r2, r3, w0, true);
        int w1 = __builtin_amdgcn_cvt_pk_fp8_f32(r4, r5, 0, false);
        w1 = __builtin_amdgcn_cvt_pk_fp8_f32(r6, r7, w1, true);
        uint2 o;
        o.x = (unsigned int)w0;
        o.y = (unsigned int)w1;
        *(uint2*)&out_f8[(size_t)row * 256 + l * 8] = o;
    } else {
        float ss = r0 * r0 + r1 * r1 + r2 * r2 + r3 * r3 + r4 * r4 + r5 * r5 + r6 * r6 + r7 * r7;
#pragma unroll
        for (int o = 1; o < 32; o <<= 1) ss += __shfl_xor(ss, o);
        float inv = 1.0f / fmaxf(sqrtf(ss), 1e-12f);
        r0 *= inv; r1 *= inv; r2 *= inv; r3 *= inv;
        r4 *= inv; r5 *= inv; r6 *= inv; r7 *= inv;
        float ss2 = r0 * r0 + r1 * r1 + r2 * r2 + r3 * r3 + r4 * r4 + r5 * r5 + r6 * r6 + r7 * r7;
#pragma unroll
        for (int o = 1; o < 32; o <<= 1) ss2 += __shfl_xor(ss2, o);
        float inv2 = 1.0f / fmaxf(sqrtf(ss2), 1e-12f);
        r0 *= inv2; r1 *= inv2; r2 *= inv2; r3 *= inv2;
        r4 *= inv2; r5 *= inv2; r6 *= inv2; r7 *= inv2;
        *(float4*)&rep[(size_t)row * 256 + l * 8] = make_float4(r0, r1, r2, r3);
        *(float4*)&rep[(size_t)row * 256 + l * 8 + 4] = make_float4(r4, r5, r6, r7);
        int w0 = __builtin_amdgcn_cvt_pk_fp8_f32(r0, r1, 0, false);
        w0 = __builtin_amdgcn_cvt_pk_fp8_f32(r2, r3, w0, true);
        int w1 = __builtin_amdgcn_cvt_pk_fp8_f32(r4, r5, 0, false);
        w1 = __builtin_amdgcn_cvt_pk_fp8_f32(r6, r7, w1, true);
        uint2 o;
        o.x = (unsigned int)w0;
        o.y = (unsigned int)w1;
        *(uint2*)&repfeat8[(size_t)row * 512 + l * 8] = o;
    }
}

// ---------------- loss helpers ----------------
__device__ __forceinline__ float dot16fp8(uint4 x, uint4 y) {
    float s = 0.f;
    const unsigned int xs[4] = {x.x, x.y, x.z, x.w};
    const unsigned int ys[4] = {y.x, y.y, y.z, y.w};
#pragma unroll
    for (int i = 0; i < 4; ++i) {
        floatx2 xl = __builtin_amdgcn_cvt_pk_f32_fp8((int)xs[i], false);
        floatx2 xh = __builtin_amdgcn_cvt_pk_f32_fp8((int)xs[i], true);
        floatx2 yl = __builtin_amdgcn_cvt_pk_f32_fp8((int)ys[i], false);
        floatx2 yh = __builtin_amdgcn_cvt_pk_f32_fp8((int)ys[i], true);
        s += xl.x * yl.x + xl.y * yl.y + xh.x * yh.x + xh.y * yh.y;
    }
    return s;
}

// ---------------- block-split loss: blocks [0,POSBLK) pos, [POSBLK,POSBLK+NEGBLK) neg ----------------
__global__ __launch_bounds__(256) void loss_both(const int2* __restrict__ posAB,
                                                 const float* __restrict__ posLS,
                                                 const int2* __restrict__ negCD,
                                                 const int* __restrict__ cnt,
                                                 const unsigned char* __restrict__ repfeat8,
                                                 float* accum) {
    const int tid = threadIdx.x;
    const int l8 = tid & 7;
    __shared__ float s[4];
    if (blockIdx.x < POSBLK) {
        const int grp = (blockIdx.x * 256 + tid) >> 3;
        const int ngrp = POSBLK * 32;
        const int P = cnt[0];
        float ap = 0.f;
        for (int g = grp; g < P; g += ngrp) {
            int2 ab = posAB[g];
            const unsigned char* pa = &repfeat8[(size_t)ab.x * 512 + l8 * 32];
            const unsigned char* pb = &repfeat8[(size_t)ab.y * 512 + l8 * 32];
            uint4 ra0 = *(const uint4*)pa;
            uint4 ra1 = *(const uint4*)(pa + 16);
            uint4 fa0 = *(const uint4*)(pa + 256);
            uint4 fa1 = *(const uint4*)(pa + 272);
            uint4 rb0 = *(const uint4*)pb;
            uint4 rb1 = *(const uint4*)(pb + 16);
            uint4 fb0 = *(const uint4*)(pb + 256);
            uint4 fb1 = *(const uint4*)(pb + 272);
            float dp = dot16fp8(ra0, rb0) + dot16fp8(ra1, rb1);
            float df = dot16fp8(fa0, fb0) + dot16fp8(fa1, fb1);
#pragma unroll
            for (int o = 1; o < 8; o <<= 1) {
                dp += __shfl_xor(dp, o);
                df += __shfl_xor(df, o);
            }
            if (l8 == 0) {
                float pw = fmaxf(dp, 0.f);
                float pos = THETA * df + (1.0f - THETA) * pw;
                float t = pos - posLS[g];
                ap += t * t;
            }
        }
#pragma unroll
        for (int o = 1; o < 64; o <<= 1) ap += __shfl_xor(ap, o);
        if ((tid & 63) == 0) s[tid >> 6] = ap;
        __syncthreads();
        if (tid == 0) unsafeAtomicAdd(&accum[0], s[0] + s[1] + s[2] + s[3]);
    } else {
        const int grp = ((blockIdx.x - POSBLK) * 256 + tid) >> 3;
        const int ngrp = NEGBLK * 32;
        const int Q = cnt[1];
        float an = 0.f;
        for (int g = grp; g < Q; g += ngrp) {
            int2 cd = negCD[g];
            const unsigned char* pc = &repfeat8[(size_t)cd.x * 512 + l8 * 32];
            const unsigned char* pd = &repfeat8[(size_t)cd.y * 512 + l8 * 32];
            uint4 rc0 = *(const uint4*)pc;
            uint4 rc1 = *(const uint4*)(pc + 16);
            uint4 rd0 = *(const uint4*)pd;
            uint4 rd1 = *(const uint4*)(pd + 16);
            float dn = dot16fp8(rc0, rd0) + dot16fp8(rc1, rd1);
#pragma unroll
            for (int o = 1; o < 8; o <<= 1) dn += __shfl_xor(dn, o);
            if (l8 == 0) {
                float nwt = fmaxf(dn, 0.f);
                an += nwt * nwt;
            }
        }
#pragma unroll
        for (int o = 1; o < 64; o <<= 1) an += __shfl_xor(an, o);
        if ((tid & 63) == 0) s[tid >> 6] = an;
        __syncthreads();
        if (tid == 0) unsafeAtomicAdd(&accum[1], s[0] + s[1] + s[2] + s[3]);
    }
}

__global__ void loss_final(const float* __restrict__ accum, const int* __restrict__ cnt,
                           float* __restrict__ out, int N) {
    out[0] = (accum[0] + accum[1]) * (float)N / (float)(cnt[0] + cnt[1]);
}

// ---------------- launcher ----------------
extern "C" void kernel_launch(void* const* d_in, const int* in_sizes, int n_in,
                              void* d_out, int out_size, void* d_ws, size_t ws_size,
                              hipStream_t stream) {
    const int* edge = (const int*)d_in[0];
    const float* features = (const float*)d_in[1];
    const float* ls = (const float*)d_in[2];
    const int* nedge = (const int*)d_in[3];
    const float* W1 = (const float*)d_in[4];
    const float* b1 = (const float*)d_in[5];
    const float* W2 = (const float*)d_in[6];
    const float* b2 = (const float*)d_in[7];
    const float* Wy = (const float*)d_in[8];
    const float* by = (const float*)d_in[9];

    const int E = in_sizes[0] / 2;
    const int N = in_sizes[1] / FEAT;
    const int* e0 = edge;
    const int* e1 = edge + E;
    const int* n0 = nedge;
    const int* n1 = nedge + E;

    float* rep = (float*)d_out;          // [N,256]
    float* rec = rep + (size_t)N * 256;  // scalar
    float* y = rec + 1;                  // [N,64], 4B-aligned only

    // workspace carve-out
    char* base = (char*)d_ws;
    size_t off = 0;
    auto carve = [&](size_t bytes) -> void* {
        void* p = base + off;
        off += (bytes + 1023) & ~(size_t)1023;
        return p;
    };
    int* deg = (int*)carve((size_t)N * 4);
    float* dinv = (float*)carve((size_t)N * 4);
    float* accum = (float*)carve(16);
    int* cnt = (int*)carve(16);
    int* rowptr = (int*)carve((size_t)(N + 1) * 4);
    int* cursor = (int*)carve((size_t)N * 4);
    int* colIdx = (int*)carve((size_t)E * 4);
    unsigned char* g8 = (unsigned char*)carve((size_t)N * 256);
    unsigned char* x18 = (unsigned char*)carve((size_t)N * 256);       // fp8 x1
    unsigned char* repfeat8 = (unsigned char*)carve((size_t)N * 512);  // rep8 | feat8
    unsigned short* Wt1 = (unsigned short*)carve(256 * 256 * 2);
    unsigned short* Wt2 = (unsigned short*)carve(256 * 256 * 2);
    unsigned short* WyT = (unsigned short*)carve(64 * 256 * 2);
    int2* posAB = (int2*)carve((size_t)E * 8);
    float* posLS = (float*)carve((size_t)E * 4);
    int2* negCD = (int2*)carve((size_t)E * 8);
    const int ebk = (E + 255) / 256;
    int* blkP = (int*)carve((size_t)ebk * 4);
    int* blkN = (int*)carve((size_t)ebk * 4);
    const int nbn = (N + 255) / 256;
    int* blkS = (int*)carve((size_t)nbn * 4);

    const int gblk = (N + 63) / 64;
    const int wblk32 = (N + 7) / 8;

    hipMemsetAsync(deg, 0, (size_t)N * 4, stream);
    hipMemsetAsync(accum, 0, 16, stream);

    // mega-prep: deg+counts | W transposes
    prep<<<ebk + 512 + 64, 256, 0, stream>>>(e0, e1, n0, n1, deg, blkP, blkN,
                                             W1, Wt1, W2, Wt2, Wy, WyT, E, ebk);

    // CSR scan chain + edge compaction (sequential writes)
    scan1_dinv<<<nbn, 256, 0, stream>>>(deg, rowptr, blkS, dinv, N);
    scan2x<<<2, 256, 0, stream>>>(blkS, nbn, blkP, blkN, cnt, ebk);
    scan3_scatter<<<nbn + ebk, 256, 0, stream>>>(rowptr, cursor, blkS, N, E, nbn,
                                                 e0, e1, n0, n1, ls, blkP, blkN, posAB, posLS, negCD);
    bucket_edges<<<ebk, 256, 0, stream>>>(e0, e1, cursor, colIdx, E);

    // conv1: g8 = fp8(dinv .* (features @ W1)); feat8 emitted alongside; x1 fp8 out
    gemm_mfma_f32A<<<gblk, 256, 0, stream>>>(features, dinv, Wt1, g8, repfeat8, N);
    spmm_gather_f8<0><<<wblk32, 256, 0, stream>>>(rowptr, colIdx, g8, dinv, b1, x18, nullptr, nullptr, N);

    // conv2: g8 = fp8(dinv .* (x1 @ W2)); fused gather + l2norm2 -> rep fp32 + rep8
    gemm_mfma_f8A<<<gblk, 256, 0, stream>>>(x18, dinv, Wt2, g8, N);
    spmm_gather_f8<1><<<wblk32, 256, 0, stream>>>(rowptr, colIdx, g8, dinv, b2, nullptr, rep, repfeat8, N);

    // y = rep8 @ Wy + by
    gemm_wy_f8A<<<gblk, 256, 0, stream>>>(repfeat8, WyT, by, y, N);

    // block-split loss (pos + neg concurrent)
    loss_both<<<POSBLK + NEGBLK, 256, 0, stream>>>(posAB, posLS, negCD, cnt, repfeat8, accum);
    loss_final<<<1, 1, 0, stream>>>(accum, cnt, rec, N);
}